// Round 5
// baseline (504.958 us; speedup 1.0000x reference)
//
#include <hip/hip_runtime.h>
#include <math.h>

#define DEV static __device__ __forceinline__

DEV double shfl8d(double v, int k){ return __shfl(v, k, 8); }
DEV double xor8d(double v, int msk){ return __shfl_xor(v, msk, 8); }
DEV float  shfl8f(float v, int k){ return __shfl(v, k, 8); }
DEV float  xor8f(float v, int msk){ return __shfl_xor(v, msk, 8); }
DEV int    xor8i(int v, int msk){ return __shfl_xor(v, msk, 8); }

DEV double sel8d(const double* a, int i){
  double v = a[0];
#pragma unroll
  for (int j=1;j<8;j++) v = (i==j) ? a[j] : v;
  return v;
}
DEV float sel8f(const float* a, int i){
  float v = a[0];
#pragma unroll
  for (int j=1;j<8;j++) v = (i==j) ? a[j] : v;
  return v;
}
DEV int sel8i(const int* a, int i){
  int v = a[0];
#pragma unroll
  for (int j=1;j<8;j++) v = (i==j) ? a[j] : v;
  return v;
}

#define CE(i,j) { double lo_ = fmin(d[i], d[j]); double hi_ = fmax(d[i], d[j]); d[i]=lo_; d[j]=hi_; }
DEV void sort8d(double* d){
  CE(0,1) CE(2,3) CE(4,5) CE(6,7)
  CE(0,2) CE(1,3) CE(4,6) CE(5,7)
  CE(1,2) CE(5,6)
  CE(0,4) CE(1,5) CE(2,6) CE(3,7)
  CE(2,4) CE(3,5)
  CE(1,2) CE(3,4) CE(5,6)
}

// ---------------------------------------------------------------------------
// kA: LeVerrier chain only. 2 matrices per 8-lane group -> register pressure
// ~130 (past the allocator's squeeze zone; R1 precedent: 140 regs, no spill).
// Bitwise-identical per-matrix op order to R1-R4. Outputs c, char, zi, scale.
// ---------------------------------------------------------------------------
__global__ __launch_bounds__(256)
__attribute__((amdgpu_waves_per_eu(1,4)))
void kA_chain(const float* __restrict__ A, double* __restrict__ ws_c,
              double* __restrict__ ws_zi, double* __restrict__ ws_scale,
              float* __restrict__ out_char, int B)
{
#pragma clang fp contract(off)
  __shared__ double sM[64*66];
  int t = blockIdx.x*256 + threadIdx.x;
  int g = t >> 3, r = t & 7;
  int m0 = 2*g, m1 = 2*g + 1;
  bool act0 = (m0 < B), act1 = (m1 < B);
  int mm0 = act0 ? m0 : 0, mm1 = act1 ? m1 : 0;
  int ml = threadIdx.x >> 3;
  double* dm0 = sM + (ml*2+0)*66;
  double* dm1 = sM + (ml*2+1)*66;

  const float* P0 = A + (size_t)mm0*64 + (size_t)r*8;
  const float* P1 = A + (size_t)mm1*64 + (size_t)r*8;
  float a0[8], a1[8];
#pragma unroll
  for (int j=0;j<8;j++){ a0[j] = P0[j]; a1[j] = P1[j]; }

  float ss0 = a0[0]*a0[0], ss1 = a1[0]*a1[0];
#pragma unroll
  for (int j=1;j<8;j++){ ss0 = ss0 + a0[j]*a0[j]; ss1 = ss1 + a1[j]*a1[j]; }
  ss0 = ss0 + xor8f(ss0,1); ss1 = ss1 + xor8f(ss1,1);
  ss0 = ss0 + xor8f(ss0,2); ss1 = ss1 + xor8f(ss1,2);
  ss0 = ss0 + xor8f(ss0,4); ss1 = ss1 + xor8f(ss1,4);
  double scale0 = fmax((double)sqrtf(ss0) / 2.8284271247461903, 1e-12);
  double scale1 = fmax((double)sqrtf(ss1) / 2.8284271247461903, 1e-12);
  double Ad0[8], Ad1[8];
#pragma unroll
  for (int j=0;j<8;j++){ Ad0[j] = (double)a0[j] / scale0; Ad1[j] = (double)a1[j] / scale1; }

  double ck0, ck1;
  // k=1: M1 = I
  {
    double s0 = Ad0[0]*((r==0)?1.0:0.0), s1 = Ad1[0]*((r==0)?1.0:0.0);
#pragma unroll
    for (int j=1;j<8;j++){ s0 = s0 + Ad0[j]*((r==j)?1.0:0.0); s1 = s1 + Ad1[j]*((r==j)?1.0:0.0); }
    s0 = s0 + xor8d(s0,1); s1 = s1 + xor8d(s1,1);
    s0 = s0 + xor8d(s0,2); s1 = s1 + xor8d(s1,2);
    s0 = s0 + xor8d(s0,4); s1 = s1 + xor8d(s1,4);
    double v0 = -s0/1.0, v1 = -s1/1.0;
    if (act0 && r == 7){ ws_c[(size_t)m0*9+7] = v0; out_char[(size_t)m0*8+7] = (float)v0; }
    if (act1 && r == 7){ ws_c[(size_t)m1*9+7] = v1; out_char[(size_t)m1*8+7] = (float)v1; }
    ck0 = v0; ck1 = v1;
  }
  double Mc0[8], Mc1[8];
#pragma unroll
  for (int j=0;j<8;j++){ Mc0[j] = Ad0[j] + ((j==r)?ck0:0.0); Mc1[j] = Ad1[j] + ((j==r)?ck1:0.0); }
  {
    double s0 = Ad0[0]*Mc0[0], s1 = Ad1[0]*Mc1[0];
#pragma unroll
    for (int j=1;j<8;j++){ s0 = s0 + Ad0[j]*Mc0[j]; s1 = s1 + Ad1[j]*Mc1[j]; }
    s0 = s0 + xor8d(s0,1); s1 = s1 + xor8d(s1,1);
    s0 = s0 + xor8d(s0,2); s1 = s1 + xor8d(s1,2);
    s0 = s0 + xor8d(s0,4); s1 = s1 + xor8d(s1,4);
    double v0 = -s0/2.0, v1 = -s1/2.0;
    if (act0 && r == 6){ ws_c[(size_t)m0*9+6] = v0; out_char[(size_t)m0*8+6] = (float)v0; }
    if (act1 && r == 6){ ws_c[(size_t)m1*9+6] = v1; out_char[(size_t)m1*8+6] = (float)v1; }
    ck0 = v0; ck1 = v1;
  }
#pragma unroll
  for (int k=3;k<=8;k++){
    double2* w0 = (double2*)(dm0 + r*8);
    w0[0]=make_double2(Mc0[0],Mc0[1]); w0[1]=make_double2(Mc0[2],Mc0[3]);
    w0[2]=make_double2(Mc0[4],Mc0[5]); w0[3]=make_double2(Mc0[6],Mc0[7]);
    double2* w1 = (double2*)(dm1 + r*8);
    w1[0]=make_double2(Mc1[0],Mc1[1]); w1[1]=make_double2(Mc1[2],Mc1[3]);
    w1[2]=make_double2(Mc1[4],Mc1[5]); w1[3]=make_double2(Mc1[6],Mc1[7]);
    __syncthreads();
    double Mn0[8], Mn1[8];
#pragma unroll
    for (int kk=0;kk<8;kk++){
      const double2* rp0 = (const double2*)(dm0 + kk*8);
      const double2* rp1 = (const double2*)(dm1 + kk*8);
      double2 p0=rp0[0],p1=rp0[1],p2=rp0[2],p3=rp0[3];
      double2 q0=rp1[0],q1=rp1[1],q2=rp1[2],q3=rp1[3];
      if (kk == 0){
        Mn0[0]=Ad0[0]*p0.x; Mn0[1]=Ad0[0]*p0.y; Mn0[2]=Ad0[0]*p1.x; Mn0[3]=Ad0[0]*p1.y;
        Mn0[4]=Ad0[0]*p2.x; Mn0[5]=Ad0[0]*p2.y; Mn0[6]=Ad0[0]*p3.x; Mn0[7]=Ad0[0]*p3.y;
        Mn1[0]=Ad1[0]*q0.x; Mn1[1]=Ad1[0]*q0.y; Mn1[2]=Ad1[0]*q1.x; Mn1[3]=Ad1[0]*q1.y;
        Mn1[4]=Ad1[0]*q2.x; Mn1[5]=Ad1[0]*q2.y; Mn1[6]=Ad1[0]*q3.x; Mn1[7]=Ad1[0]*q3.y;
      } else {
        Mn0[0]=fma(Ad0[kk],p0.x,Mn0[0]); Mn0[1]=fma(Ad0[kk],p0.y,Mn0[1]);
        Mn0[2]=fma(Ad0[kk],p1.x,Mn0[2]); Mn0[3]=fma(Ad0[kk],p1.y,Mn0[3]);
        Mn0[4]=fma(Ad0[kk],p2.x,Mn0[4]); Mn0[5]=fma(Ad0[kk],p2.y,Mn0[5]);
        Mn0[6]=fma(Ad0[kk],p3.x,Mn0[6]); Mn0[7]=fma(Ad0[kk],p3.y,Mn0[7]);
        Mn1[0]=fma(Ad1[kk],q0.x,Mn1[0]); Mn1[1]=fma(Ad1[kk],q0.y,Mn1[1]);
        Mn1[2]=fma(Ad1[kk],q1.x,Mn1[2]); Mn1[3]=fma(Ad1[kk],q1.y,Mn1[3]);
        Mn1[4]=fma(Ad1[kk],q2.x,Mn1[4]); Mn1[5]=fma(Ad1[kk],q2.y,Mn1[5]);
        Mn1[6]=fma(Ad1[kk],q3.x,Mn1[6]); Mn1[7]=fma(Ad1[kk],q3.y,Mn1[7]);
      }
    }
    __syncthreads();
#pragma unroll
    for (int j=0;j<8;j++){ Mc0[j] = Mn0[j] + ((j==r)?ck0:0.0); Mc1[j] = Mn1[j] + ((j==r)?ck1:0.0); }
    double s0 = Ad0[0]*Mc0[0], s1 = Ad1[0]*Mc1[0];
#pragma unroll
    for (int j=1;j<8;j++){ s0 = s0 + Ad0[j]*Mc0[j]; s1 = s1 + Ad1[j]*Mc1[j]; }
    s0 = s0 + xor8d(s0,1); s1 = s1 + xor8d(s1,1);
    s0 = s0 + xor8d(s0,2); s1 = s1 + xor8d(s1,2);
    s0 = s0 + xor8d(s0,4); s1 = s1 + xor8d(s1,4);
    double v0 = (-s0)/(double)k, v1 = (-s1)/(double)k;
    int idx = 8 - k;
    if (act0 && r == idx){ ws_c[(size_t)m0*9+idx] = v0; out_char[(size_t)m0*8+idx] = (float)v0; }
    if (act1 && r == idx){ ws_c[(size_t)m1*9+idx] = v1; out_char[(size_t)m1*8+idx] = (float)v1; }
    ck0 = v0; ck1 = v1;
  }

  // zi = sort(diag(Ad)) + linspace(-1e-4, 1e-4, 8)
  {
    double diag0 = sel8d(Ad0, r), diag1 = sel8d(Ad1, r);
    double d[8];
#pragma unroll
    for (int k=0;k<8;k++) d[k] = shfl8d(diag0, k);
    sort8d(d);
    double step = 2e-4/7.0;
    double lin = (double)r * step + (-1e-4);
    if (r == 7) lin = 1e-4;
    if (act0) ws_zi[(size_t)m0*8 + r] = sel8d(d, r) + lin;
#pragma unroll
    for (int k=0;k<8;k++) d[k] = shfl8d(diag1, k);
    sort8d(d);
    if (act1) ws_zi[(size_t)m1*8 + r] = sel8d(d, r) + lin;
  }
  if (act0 && r == 0) ws_scale[m0] = scale0;
  if (act1 && r == 0) ws_scale[m1] = scale1;
}

// ---------------------------------------------------------------------------
// kB: Laguerre rings + deflation only. 8-lane redundant (free in SIMT), live
// set ~50 regs -> genuinely fits 64, no spill, 8 waves/SIMD. Ring body is the
// R4 section verbatim; cl/zi round-trip through f64 global is bit-preserving.
// ---------------------------------------------------------------------------
__global__ __launch_bounds__(256)
void kB_rings(const double* __restrict__ ws_c, const double* __restrict__ ws_zi,
              double* __restrict__ ws_lam, float* __restrict__ ws_fr,
              float* __restrict__ ws_st, int B)
{
#pragma clang fp contract(off)
  int t = blockIdx.x*256 + threadIdx.x;
  int m = t >> 3, r = t & 7;
  bool act = (m < B);
  if (!act) m = 0;
  const double* cp = ws_c + (size_t)m*9;
  double cl[9];
#pragma unroll
  for (int j=0;j<8;j++) cl[j] = cp[j];
  cl[8] = 1.0;
  const double* zp = ws_zi + (size_t)m*8;
#pragma unroll
  for (int ri=0;ri<8;ri++){
    const int deg = 8 - ri;
    double z = zp[ri];
    float fr = 0.0f, st = 5.0f;
#pragma unroll
    for (int li=0; li<5; li++){
      double pv = cl[deg], dp = 0.0, d2 = 0.0;
#pragma unroll
      for (int j=deg-1;j>=0;j--){
        d2 = d2*z + dp;
        dp = dp*z + pv;
        pv = pv*z + cl[j];
      }
      float dp_abs = (float)fabs(dp);
      fr = fr + 1.0f/(dp_abs + 1e-8f);
      float pv_abs = (float)fabs(pv);
      if ((pv_abs < 1e-6f) && (st == 5.0f)) st = (float)li;
      bool ok = fabs(pv) > 1e-30;
      double ps = ok ? pv : 1.0;
      double G  = ok ? dp/ps : 0.0;
      double t2 = ok ? (2.0*d2)/ps : 0.0;
      double GG = G*G;
      double H  = GG - t2;
      double t3 = (double)deg*H - GG;
      double t4 = ((double)deg - 1.0) * t3;
      double disc = (t4 < 0.0) ? 0.0 : t4;
      double sq = sqrt(disc);
      double gp = G + sq, gm = G - sq;
      double den = (fabs(gp) >= fabs(gm)) ? gp : gm;
      bool dok = fabs(den) > 1e-20;
      double dsv = dok ? den : 1.0;
      z = z - (dok ? (double)deg/dsv : 0.0);
    }
    if (act && r == ri){
      ws_lam[(size_t)m*8 + ri] = z;
      ws_fr[(size_t)m*8 + ri] = fr;
      ws_st[(size_t)m*8 + ri] = st;
    }
    double b = cl[deg];
    double nc[8];
#pragma unroll
    for (int j=deg-1;j>=1;j--){
      double bn = cl[j] + z*b;
      nc[j] = b;
      b = bn;
    }
    nc[0] = b;
#pragma unroll
    for (int j=0;j<deg;j++) cl[j] = nc[j];
  }
}

// ---------------------------------------------------------------------------
// kC: polish (f64, bitwise) + FUSED chain+resolvent (R_i = R_i*lam_i + M_k as
// each M_k is produced -> no M[7][8] array; RR[2][8][8]=128 regs forces a
// 256-reg 2-wave allocation, no spill) + NS + outputs. 2 matrices per group,
// block=128, LDS 36 KB (4 blocks/CU).
// ---------------------------------------------------------------------------
__global__ __launch_bounds__(128)
__attribute__((amdgpu_waves_per_eu(1,2)))
void kC_eig(const float* __restrict__ A, const double* __restrict__ ws_c,
            const double* __restrict__ ws_lam, const double* __restrict__ ws_scale,
            const float* __restrict__ ws_fr, const float* __restrict__ ws_st,
            float* __restrict__ out, int B)
{
#pragma clang fp contract(off)
  __shared__ float sV[32*72], sY[32*72], sT[32*72], sX[32*72];
  int t = blockIdx.x*128 + threadIdx.x;
  int g = t >> 3, r = t & 7;
  int m0 = 2*g, m1 = 2*g + 1;
  bool act0 = (m0 < B), act1 = (m1 < B);
  int mm0 = act0 ? m0 : 0, mm1 = act1 ? m1 : 0;
  int ml = threadIdx.x >> 3;           // 0..15
  float* mV0 = sV + (ml*2+0)*72;  float* mV1 = sV + (ml*2+1)*72;
  float* mY0 = sY + (ml*2+0)*72;  float* mY1 = sY + (ml*2+1)*72;
  float* mT0 = sT + (ml*2+0)*72;  float* mT1 = sT + (ml*2+1)*72;
  float* mX0 = sX + (ml*2+0)*72;  float* mX1 = sX + (ml*2+1)*72;

  // ---- Newton polish: lane r polishes root r of both matrices ----
  const double* cp0 = ws_c + (size_t)mm0*9;
  const double* cp1 = ws_c + (size_t)mm1*9;
  double cd0[8], cd1[8];
#pragma unroll
  for (int j=0;j<8;j++){ cd0[j] = cp0[j]; cd1[j] = cp1[j]; }
  double z0 = ws_lam[(size_t)mm0*8 + r];
  double z1 = ws_lam[(size_t)mm1*8 + r];
#pragma unroll
  for (int it=0; it<3; it++){
    double pv0 = 1.0, dp0 = 0.0, pv1 = 1.0, dp1 = 0.0;
#pragma unroll
    for (int j=7;j>=0;j--){
      dp0 = dp0*z0 + pv0; pv0 = pv0*z0 + cd0[j];
      dp1 = dp1*z1 + pv1; pv1 = pv1*z1 + cd1[j];
    }
    bool ok0 = fabs(dp0) > 1e-30, ok1 = fabs(dp1) > 1e-30;
    z0 = z0 - (ok0 ? pv0/(ok0?dp0:1.0) : 0.0);
    z1 = z1 - (ok1 ? pv1/(ok1?dp1:1.0) : 0.0);
  }
  float lamf0[8], lamf1[8];
#pragma unroll
  for (int j=0;j<8;j++){ lamf0[j] = (float)shfl8d(z0, j); lamf1[j] = (float)shfl8d(z1, j); }
  float cc0[8], cc1[8];
#pragma unroll
  for (int j=1;j<8;j++){ cc0[j] = (float)cd0[j]; cc1[j] = (float)cd1[j]; }

  const float* P0 = A + (size_t)mm0*64 + (size_t)r*8;
  const float* P1 = A + (size_t)mm1*64 + (size_t)r*8;
  float a0[8], a1[8];
#pragma unroll
  for (int j=0;j<8;j++){ a0[j] = P0[j]; a1[j] = P1[j]; }
  float sc0 = (float)ws_scale[mm0], sc1 = (float)ws_scale[mm1];
  float Af0[8], Af1[8];
#pragma unroll
  for (int j=0;j<8;j++){ Af0[j] = a0[j]/sc0; Af1[j] = a1[j]/sc1; }

  // ---- fused chain + resolvent Horner ----
  float RR0[8][8], RR1[8][8];
#pragma unroll
  for (int i=0;i<8;i++)
#pragma unroll
    for (int j=0;j<8;j++){ float idv = (j==r)?1.0f:0.0f; RR0[i][j] = idv; RR1[i][j] = idv; }
  float Mc0[8], Mc1[8];
#pragma unroll
  for (int j=0;j<8;j++){ Mc0[j] = Af0[j] + ((j==r)?cc0[7]:0.0f); Mc1[j] = Af1[j] + ((j==r)?cc1[7]:0.0f); }
#pragma unroll
  for (int i=0;i<8;i++)
#pragma unroll
    for (int j=0;j<8;j++){
      RR0[i][j] = fmaf(RR0[i][j], lamf0[i], Mc0[j]);
      RR1[i][j] = fmaf(RR1[i][j], lamf1[i], Mc1[j]);
    }
#pragma unroll
  for (int k=3;k<=8;k++){
    float4* w0 = (float4*)(mV0 + r*8);
    w0[0] = make_float4(Mc0[0],Mc0[1],Mc0[2],Mc0[3]);
    w0[1] = make_float4(Mc0[4],Mc0[5],Mc0[6],Mc0[7]);
    float4* w1 = (float4*)(mV1 + r*8);
    w1[0] = make_float4(Mc1[0],Mc1[1],Mc1[2],Mc1[3]);
    w1[1] = make_float4(Mc1[4],Mc1[5],Mc1[6],Mc1[7]);
    __syncthreads();
    float Mn0[8], Mn1[8];
#pragma unroll
    for (int kk=0;kk<8;kk++){
      const float4* rp0 = (const float4*)(mV0 + kk*8);
      const float4* rp1 = (const float4*)(mV1 + kk*8);
      float4 lo0 = rp0[0], hi0 = rp0[1], lo1 = rp1[0], hi1 = rp1[1];
      if (kk == 0){
        Mn0[0]=Af0[0]*lo0.x; Mn0[1]=Af0[0]*lo0.y; Mn0[2]=Af0[0]*lo0.z; Mn0[3]=Af0[0]*lo0.w;
        Mn0[4]=Af0[0]*hi0.x; Mn0[5]=Af0[0]*hi0.y; Mn0[6]=Af0[0]*hi0.z; Mn0[7]=Af0[0]*hi0.w;
        Mn1[0]=Af1[0]*lo1.x; Mn1[1]=Af1[0]*lo1.y; Mn1[2]=Af1[0]*lo1.z; Mn1[3]=Af1[0]*lo1.w;
        Mn1[4]=Af1[0]*hi1.x; Mn1[5]=Af1[0]*hi1.y; Mn1[6]=Af1[0]*hi1.z; Mn1[7]=Af1[0]*hi1.w;
      } else {
        Mn0[0]=fmaf(Af0[kk],lo0.x,Mn0[0]); Mn0[1]=fmaf(Af0[kk],lo0.y,Mn0[1]);
        Mn0[2]=fmaf(Af0[kk],lo0.z,Mn0[2]); Mn0[3]=fmaf(Af0[kk],lo0.w,Mn0[3]);
        Mn0[4]=fmaf(Af0[kk],hi0.x,Mn0[4]); Mn0[5]=fmaf(Af0[kk],hi0.y,Mn0[5]);
        Mn0[6]=fmaf(Af0[kk],hi0.z,Mn0[6]); Mn0[7]=fmaf(Af0[kk],hi0.w,Mn0[7]);
        Mn1[0]=fmaf(Af1[kk],lo1.x,Mn1[0]); Mn1[1]=fmaf(Af1[kk],lo1.y,Mn1[1]);
        Mn1[2]=fmaf(Af1[kk],lo1.z,Mn1[2]); Mn1[3]=fmaf(Af1[kk],lo1.w,Mn1[3]);
        Mn1[4]=fmaf(Af1[kk],hi1.x,Mn1[4]); Mn1[5]=fmaf(Af1[kk],hi1.y,Mn1[5]);
        Mn1[6]=fmaf(Af1[kk],hi1.z,Mn1[6]); Mn1[7]=fmaf(Af1[kk],hi1.w,Mn1[7]);
      }
    }
    __syncthreads();
    float ckf0 = cc0[9-k], ckf1 = cc1[9-k];
#pragma unroll
    for (int j=0;j<8;j++){ Mc0[j] = Mn0[j] + ((j==r)?ckf0:0.0f); Mc1[j] = Mn1[j] + ((j==r)?ckf1:0.0f); }
#pragma unroll
    for (int i=0;i<8;i++)
#pragma unroll
      for (int j=0;j<8;j++){
        RR0[i][j] = fmaf(RR0[i][j], lamf0[i], Mc0[j]);
        RR1[i][j] = fmaf(RR1[i][j], lamf1[i], Mc1[j]);
      }
  }

  // ---- per eigenvalue: row-norm butterfly argmax, normalized vector ----
  float Vrow0[8], Vrow1[8];
#pragma unroll
  for (int i=0;i<8;i++){
    float nsq0 = RR0[i][0]*RR0[i][0], nsq1 = RR1[i][0]*RR1[i][0];
#pragma unroll
    for (int j=1;j<8;j++){ nsq0 = fmaf(RR0[i][j],RR0[i][j],nsq0); nsq1 = fmaf(RR1[i][j],RR1[i][j],nsq1); }
    int bi0 = r, bi1 = r; float bv0 = nsq0, bv1 = nsq1;
#pragma unroll
    for (int lvl=1; lvl<8; lvl<<=1){
      float ov0 = xor8f(bv0, lvl), ov1 = xor8f(bv1, lvl);
      int   oi0 = xor8i(bi0, lvl), oi1 = xor8i(bi1, lvl);
      bool tk0 = (ov0 > bv0) || ((ov0 == bv0) && (oi0 < bi0));
      bool tk1 = (ov1 > bv1) || ((ov1 == bv1) && (oi1 < bi1));
      bv0 = tk0 ? ov0 : bv0; bi0 = tk0 ? oi0 : bi0;
      bv1 = tk1 ? ov1 : bv1; bi1 = tk1 ? oi1 : bi1;
    }
    Vrow0[i] = sel8f(RR0[i], bi0) / (sqrtf(bv0) + 1e-30f);
    Vrow1[i] = sel8f(RR1[i], bi1) / (sqrtf(bv1) + 1e-30f);
  }

  // ---- f32 Newton-Schulz (both matrices interleaved between barriers) ----
  __syncthreads();
#pragma unroll
  for (int j=0;j<8;j++){ mV0[r*9+j] = Vrow0[j]; mV1[r*9+j] = Vrow1[j]; }
  __syncthreads();
  float Yrow0[8], Yrow1[8];
#pragma unroll
  for (int j=0;j<8;j++){
    float s0 = 0.0f, s1 = 0.0f;
#pragma unroll
    for (int k=0;k<8;k++){ s0 = fmaf(mV0[k*9+r], mV0[k*9+j], s0); s1 = fmaf(mV1[k*9+r], mV1[k*9+j], s1); }
    Yrow0[j] = s0; Yrow1[j] = s1;
  }
  float Xrow0[8], Xrow1[8];
#pragma unroll
  for (int j=0;j<8;j++){ float idv = (j==r)?1.0f:0.0f; Xrow0[j] = idv; Xrow1[j] = idv; }
#pragma unroll
  for (int j=0;j<8;j++){ mY0[r*9+j] = Yrow0[j]; mY1[r*9+j] = Yrow1[j]; }
  __syncthreads();
#pragma unroll
  for (int it=0; it<2; it++){
    float Trow0[8], Trow1[8];
#pragma unroll
    for (int j=0;j<8;j++){
      float d3 = (j==r)?3.0f:0.0f;
      Trow0[j] = d3 - Yrow0[j]; Trow1[j] = d3 - Yrow1[j];
      mT0[r*9+j] = Trow0[j];    mT1[r*9+j] = Trow1[j];
    }
    __syncthreads();
    float Xn0[8], Yn0[8], Xn1[8], Yn1[8];
#pragma unroll
    for (int j=0;j<8;j++){
      float s0 = 0.0f, s1 = 0.0f;
#pragma unroll
      for (int k=0;k<8;k++){ s0 = fmaf(Xrow0[k], mT0[k*9+j], s0); s1 = fmaf(Xrow1[k], mT1[k*9+j], s1); }
      Xn0[j] = 0.5f*s0; Xn1[j] = 0.5f*s1;
    }
#pragma unroll
    for (int j=0;j<8;j++){
      float s0 = 0.0f, s1 = 0.0f;
#pragma unroll
      for (int k=0;k<8;k++){ s0 = fmaf(Trow0[k], mY0[k*9+j], s0); s1 = fmaf(Trow1[k], mY1[k*9+j], s1); }
      Yn0[j] = 0.5f*s0; Yn1[j] = 0.5f*s1;
    }
    __syncthreads();
#pragma unroll
    for (int j=0;j<8;j++){
      mY0[r*9+j] = Yn0[j]; Yrow0[j] = Yn0[j]; Xrow0[j] = Xn0[j];
      mY1[r*9+j] = Yn1[j]; Yrow1[j] = Yn1[j]; Xrow1[j] = Xn1[j];
    }
    __syncthreads();
  }
#pragma unroll
  for (int j=0;j<8;j++){ mX0[r*9+j] = Xrow0[j]; mX1[r*9+j] = Xrow1[j]; }
  __syncthreads();
  float Vn0[8], Vn1[8];
#pragma unroll
  for (int j=0;j<8;j++){
    float s0 = 0.0f, s1 = 0.0f;
#pragma unroll
    for (int k=0;k<8;k++){ s0 = fmaf(Vrow0[k], mX0[k*9+j], s0); s1 = fmaf(Vrow1[k], mX1[k*9+j], s1); }
    Vn0[j] = s0; Vn1[j] = s1;
  }
  __syncthreads();
#pragma unroll
  for (int j=0;j<8;j++){ mV0[r*9+j] = Vn0[j]; mV1[r*9+j] = Vn1[j]; }
  __syncthreads();
  float Erow0[8], Erow1[8];
#pragma unroll
  for (int j=0;j<8;j++){
    float s0 = 0.0f, s1 = 0.0f;
#pragma unroll
    for (int k=0;k<8;k++){ s0 = fmaf(mV0[k*9+r], mV0[k*9+j], s0); s1 = fmaf(mV1[k*9+r], mV1[k*9+j], s1); }
    float idv = (j==r)?1.0f:0.0f;
    Erow0[j] = s0 - idv; Erow1[j] = s1 - idv;
  }
  float rs0 = Erow0[0]*Erow0[0], rs1 = Erow1[0]*Erow1[0];
#pragma unroll
  for (int j=1;j<8;j++){ rs0 = rs0 + Erow0[j]*Erow0[j]; rs1 = rs1 + Erow1[j]*Erow1[j]; }
  rs0 = rs0 + xor8f(rs0,1); rs1 = rs1 + xor8f(rs1,1);
  rs0 = rs0 + xor8f(rs0,2); rs1 = rs1 + xor8f(rs1,2);
  rs0 = rs0 + xor8f(rs0,4); rs1 = rs1 + xor8f(rs1,4);
  float resid0 = sqrtf(rs0), resid1 = sqrtf(rs1);
  float AV0[8], AV1[8];
#pragma unroll
  for (int j=0;j<8;j++){
    float s0 = 0.0f, s1 = 0.0f;
#pragma unroll
    for (int k=0;k<8;k++){ s0 = fmaf(a0[k], mV0[k*9+j], s0); s1 = fmaf(a1[k], mV1[k*9+j], s1); }
    AV0[j] = s0; AV1[j] = s1;
  }
  float ev0[8], ev1[8];
#pragma unroll
  for (int i=0;i<8;i++){
    float q0 = Vn0[i]*AV0[i], q1 = Vn1[i]*AV1[i];
    float s0 = shfl8f(q0, 0), s1 = shfl8f(q1, 0);
#pragma unroll
    for (int k=1;k<8;k++){ s0 = s0 + shfl8f(q0, k); s1 = s1 + shfl8f(q1, k); }
    ev0[i] = s0; ev1[i] = s1;
  }
  int perm0[8], perm1[8];
  {
    unsigned u0 = 0, u1 = 0;
#pragma unroll
    for (int p=0;p<8;p++){
      int b0 = -1, b1 = -1; float v0 = 0.0f, v1 = 0.0f;
#pragma unroll
      for (int i2=0;i2<8;i2++){
        bool used0 = (u0 >> i2) & 1u, used1 = (u1 >> i2) & 1u;
        bool t0 = !used0 && (b0 < 0 || ev0[i2] < v0);
        bool t1 = !used1 && (b1 < 0 || ev1[i2] < v1);
        b0 = t0 ? i2 : b0; v0 = t0 ? ev0[i2] : v0;
        b1 = t1 ? i2 : b1; v1 = t1 ? ev1[i2] : v1;
      }
      perm0[p] = b0; u0 |= (1u << b0);
      perm1[p] = b1; u1 |= (1u << b1);
    }
  }
  int oi0 = sel8i(perm0, r), oi1 = sel8i(perm1, r);
  float col0[8], col1[8];
#pragma unroll
  for (int j=0;j<8;j++){ col0[j] = mV0[j*9 + oi0]; col1[j] = mV1[j*9 + oi1]; }
  int mi0 = 0, mi1 = 0; float mv0 = fabsf(col0[0]), mv1 = fabsf(col1[0]);
#pragma unroll
  for (int j=1;j<8;j++){
    float aj0 = fabsf(col0[j]), aj1 = fabsf(col1[j]);
    if (aj0 > mv0){ mv0 = aj0; mi0 = j; }
    if (aj1 > mv1){ mv1 = aj1; mi1 = j; }
  }
  float w0 = sel8f(col0, mi0), w1 = sel8f(col1, mi1);
  float sg0 = (w0 > 0.0f) ? 1.0f : ((w0 < 0.0f) ? -1.0f : w0);
  float sg1 = (w1 > 0.0f) ? 1.0f : ((w1 < 0.0f) ? -1.0f : w1);
  if (act0){
    out[(size_t)m0*8 + r] = sel8f(ev0, oi0);
    float* svp = out + (size_t)B*8 + (size_t)m0*64;
#pragma unroll
    for (int j=0;j<8;j++) svp[(size_t)j*8 + r] = col0[j]*sg0;
    out[(size_t)B*80 + (size_t)m0*8 + r] = ws_fr[(size_t)m0*8 + oi0];
    out[(size_t)B*88 + (size_t)m0*8 + r] = ws_st[(size_t)m0*8 + oi0];
    out[(size_t)B*96 + (size_t)m0*8 + r] = (float)r;
    if (r == 0) out[(size_t)B*104 + m0] = resid0;
  }
  if (act1){
    out[(size_t)m1*8 + r] = sel8f(ev1, oi1);
    float* svp = out + (size_t)B*8 + (size_t)m1*64;
#pragma unroll
    for (int j=0;j<8;j++) svp[(size_t)j*8 + r] = col1[j]*sg1;
    out[(size_t)B*80 + (size_t)m1*8 + r] = ws_fr[(size_t)m1*8 + oi1];
    out[(size_t)B*88 + (size_t)m1*8 + r] = ws_st[(size_t)m1*8 + oi1];
    out[(size_t)B*96 + (size_t)m1*8 + r] = (float)r;
    if (r == 0) out[(size_t)B*104 + m1] = resid1;
  }
}

extern "C" void kernel_launch(void* const* d_in, const int* in_sizes, int n_in,
                              void* d_out, int out_size, void* d_ws, size_t ws_size,
                              hipStream_t stream) {
  const float* A = (const float*)d_in[0];
  int B = in_sizes[0] / 64;
  float* out = (float*)d_out;

  double* ws_c     = (double*)d_ws;                 // B*9 f64
  double* ws_zi    = ws_c   + (size_t)B*9;          // B*8 f64
  double* ws_lam   = ws_zi  + (size_t)B*8;          // B*8 f64
  double* ws_scale = ws_lam + (size_t)B*8;          // B   f64
  float*  ws_fr    = (float*)(ws_scale + B);        // B*8 f32
  float*  ws_st    = ws_fr  + (size_t)B*8;          // B*8 f32

  int groups = (B + 1) / 2;
  int thrA = groups * 8;
  hipLaunchKernelGGL(kA_chain, dim3((thrA+255)/256), dim3(256), 0, stream,
                     A, ws_c, ws_zi, ws_scale, out + (size_t)B*72, B);
  hipLaunchKernelGGL(kB_rings, dim3((B*8+255)/256), dim3(256), 0, stream,
                     ws_c, ws_zi, ws_lam, ws_fr, ws_st, B);
  hipLaunchKernelGGL(kC_eig, dim3((thrA+127)/128), dim3(128), 0, stream,
                     A, ws_c, ws_lam, ws_scale, ws_fr, ws_st, out, B);
}

// Round 6
// 186.409 us; speedup vs baseline: 2.7089x; 2.7089x over previous
//
#include <hip/hip_runtime.h>
#include <math.h>

#define DEV static __device__ __forceinline__

DEV double shfl8d(double v, int k){ return __shfl(v, k, 8); }
DEV double xor8d(double v, int msk){ return __shfl_xor(v, msk, 8); }
DEV float  shfl8f(float v, int k){ return __shfl(v, k, 8); }
DEV float  xor8f(float v, int msk){ return __shfl_xor(v, msk, 8); }
DEV int    xor8i(int v, int msk){ return __shfl_xor(v, msk, 8); }

DEV double sel8d(const double* a, int i){
  double v = a[0];
#pragma unroll
  for (int j=1;j<8;j++) v = (i==j) ? a[j] : v;
  return v;
}
DEV float sel8f(const float* a, int i){
  float v = a[0];
#pragma unroll
  for (int j=1;j<8;j++) v = (i==j) ? a[j] : v;
  return v;
}
DEV int sel8i(const int* a, int i){
  int v = a[0];
#pragma unroll
  for (int j=1;j<8;j++) v = (i==j) ? a[j] : v;
  return v;
}

#define CE(i,j) { double lo_ = fmin(d[i], d[j]); double hi_ = fmax(d[i], d[j]); d[i]=lo_; d[j]=hi_; }

// ---------------------------------------------------------------------------
// k1: LeVerrier chain, 1 matrix per 8-lane group. REGISTER DIET: no c[9]
// array (each c_k streamed to global the moment it exists; rolling ck only),
// Mc regs dead while the matrix sits in LDS. True peak ~48-56 VGPR -> the
// allocator's 64-reg/8-wave choice carries NO spills (R2-R5 lesson: any
// design >64 true live spills; attributes can't prevent it).
// Arithmetic bitwise-identical to the R1-R5 passing chain.
// ---------------------------------------------------------------------------
__global__ __launch_bounds__(256)
void k1_chain(const float* __restrict__ A, double* __restrict__ ws_c,
              double* __restrict__ ws_zi, double* __restrict__ ws_scale,
              float* __restrict__ out_char, int B)
{
#pragma clang fp contract(off)
  __shared__ double sM[32*66];
  int t = blockIdx.x*256 + threadIdx.x;
  int m = t >> 3, r = t & 7;
  bool act = (m < B);
  if (!act) m = 0;
  double* dm = sM + (threadIdx.x >> 3)*66;

  const float* Am = A + (size_t)m*64 + (size_t)r*8;
  float af[8];
#pragma unroll
  for (int j=0;j<8;j++) af[j] = Am[j];
  float ss = af[0]*af[0];
#pragma unroll
  for (int j=1;j<8;j++) ss = ss + af[j]*af[j];
  ss = ss + xor8f(ss,1);
  ss = ss + xor8f(ss,2);
  ss = ss + xor8f(ss,4);
  float nrm = sqrtf(ss);
  double scale = fmax((double)nrm / 2.8284271247461903, 1e-12);
  double Ad[8];
#pragma unroll
  for (int j=0;j<8;j++) Ad[j] = (double)af[j] / scale;

  double ck;
  // k=1: M1 = I (trace formula identical to prior rounds)
  {
    double s = Ad[0] * ((r==0)?1.0:0.0);
#pragma unroll
    for (int j=1;j<8;j++) s = s + Ad[j] * ((r==j)?1.0:0.0);
    s = s + xor8d(s,1);
    s = s + xor8d(s,2);
    s = s + xor8d(s,4);
    ck = -s / 1.0;
    if (act && r == 7){ ws_c[(size_t)m*9+7] = ck; out_char[(size_t)m*8+7] = (float)ck; }
  }
  double Mc[8];
#pragma unroll
  for (int j=0;j<8;j++) Mc[j] = Ad[j] + ((j==r) ? ck : 0.0);
  {
    double s = Ad[0]*Mc[0];
#pragma unroll
    for (int j=1;j<8;j++) s = s + Ad[j]*Mc[j];
    s = s + xor8d(s,1);
    s = s + xor8d(s,2);
    s = s + xor8d(s,4);
    ck = -s / 2.0;
    if (act && r == 6){ ws_c[(size_t)m*9+6] = ck; out_char[(size_t)m*8+6] = (float)ck; }
  }
#pragma unroll
  for (int k=3;k<=8;k++){
    double2* rowp = (double2*)(dm + r*8);
    rowp[0] = make_double2(Mc[0], Mc[1]);
    rowp[1] = make_double2(Mc[2], Mc[3]);
    rowp[2] = make_double2(Mc[4], Mc[5]);
    rowp[3] = make_double2(Mc[6], Mc[7]);
    __syncthreads();
    double Mn[8];
#pragma unroll
    for (int kk=0;kk<8;kk++){
      const double2* rp = (const double2*)(dm + kk*8);
      double2 q0 = rp[0], q1 = rp[1], q2 = rp[2], q3 = rp[3];
      if (kk == 0){
        Mn[0]=Ad[0]*q0.x; Mn[1]=Ad[0]*q0.y; Mn[2]=Ad[0]*q1.x; Mn[3]=Ad[0]*q1.y;
        Mn[4]=Ad[0]*q2.x; Mn[5]=Ad[0]*q2.y; Mn[6]=Ad[0]*q3.x; Mn[7]=Ad[0]*q3.y;
      } else {
        Mn[0]=fma(Ad[kk],q0.x,Mn[0]); Mn[1]=fma(Ad[kk],q0.y,Mn[1]);
        Mn[2]=fma(Ad[kk],q1.x,Mn[2]); Mn[3]=fma(Ad[kk],q1.y,Mn[3]);
        Mn[4]=fma(Ad[kk],q2.x,Mn[4]); Mn[5]=fma(Ad[kk],q2.y,Mn[5]);
        Mn[6]=fma(Ad[kk],q3.x,Mn[6]); Mn[7]=fma(Ad[kk],q3.y,Mn[7]);
      }
    }
    __syncthreads();
#pragma unroll
    for (int j=0;j<8;j++) Mc[j] = Mn[j] + ((j==r) ? ck : 0.0);
    double s = Ad[0]*Mc[0];
#pragma unroll
    for (int j=1;j<8;j++) s = s + Ad[j]*Mc[j];
    s = s + xor8d(s,1);
    s = s + xor8d(s,2);
    s = s + xor8d(s,4);
    ck = (-s) / (double)k;
    int idx = 8 - k;
    if (act && r == idx){ ws_c[(size_t)m*9+idx] = ck; out_char[(size_t)m*8+idx] = (float)ck; }
  }
  if (act && r == 0) ws_scale[m] = scale;

  // zi = sort(diag(Ad)) + linspace(-1e-4, 1e-4, 8)
  double diag = sel8d(Ad, r);
  double d[8];
#pragma unroll
  for (int k=0;k<8;k++) d[k] = shfl8d(diag, k);
  CE(0,1) CE(2,3) CE(4,5) CE(6,7)
  CE(0,2) CE(1,3) CE(4,6) CE(5,7)
  CE(1,2) CE(5,6)
  CE(0,4) CE(1,5) CE(2,6) CE(3,7)
  CE(2,4) CE(3,5)
  CE(1,2) CE(3,4) CE(5,6)
  double step = 2e-4/7.0;
  double lin = (double)r * step + (-1e-4);
  if (r == 7) lin = 1e-4;
  if (act) ws_zi[(size_t)m*8 + r] = sel8d(d, r) + lin;
}

// ---------------------------------------------------------------------------
// k2: Laguerre rings + deflation, 1 thread/matrix. REGISTER DIET: no polish
// (lives in k3), no c[9]/roots[8] arrays -> ~45 live doubles-equivalents ->
// fits the 64-reg allocation with NO scratch (R2's k2 was scratch-latency
// bound at 1 wave/SIMD). Ring body verbatim from the passing R3/R5 source.
// ---------------------------------------------------------------------------
__global__ __launch_bounds__(256)
void k2_rings(const double* __restrict__ ws_c, const double* __restrict__ ws_zi,
              double* __restrict__ ws_lam, float* __restrict__ ws_fr,
              float* __restrict__ ws_st, int B)
{
#pragma clang fp contract(off)
  int m = blockIdx.x*256 + threadIdx.x;
  if (m >= B) return;
  const double* cp = ws_c + (size_t)m*9;
  double cl[9];
#pragma unroll
  for (int j=0;j<8;j++) cl[j] = cp[j];
  cl[8] = 1.0;
  const double* zp = ws_zi + (size_t)m*8;
#pragma unroll
  for (int ri=0;ri<8;ri++){
    const int deg = 8 - ri;
    double z = zp[ri];
    float fr = 0.0f, st = 5.0f;
#pragma unroll
    for (int li=0; li<5; li++){
      double pv = cl[deg], dp = 0.0, d2 = 0.0;
#pragma unroll
      for (int j=deg-1;j>=0;j--){
        d2 = d2*z + dp;
        dp = dp*z + pv;
        pv = pv*z + cl[j];
      }
      float dp_abs = (float)fabs(dp);
      fr = fr + 1.0f/(dp_abs + 1e-8f);
      float pv_abs = (float)fabs(pv);
      if ((pv_abs < 1e-6f) && (st == 5.0f)) st = (float)li;
      bool ok = fabs(pv) > 1e-30;
      double ps = ok ? pv : 1.0;
      double G  = ok ? dp/ps : 0.0;
      double t2 = ok ? (2.0*d2)/ps : 0.0;
      double GG = G*G;
      double H  = GG - t2;
      double t3 = (double)deg*H - GG;
      double t4 = ((double)deg - 1.0) * t3;
      double disc = (t4 < 0.0) ? 0.0 : t4;
      double sq = sqrt(disc);
      double gp = G + sq, gm = G - sq;
      double den = (fabs(gp) >= fabs(gm)) ? gp : gm;
      bool dok = fabs(den) > 1e-20;
      double dsv = dok ? den : 1.0;
      z = z - (dok ? (double)deg/dsv : 0.0);
    }
    ws_lam[(size_t)m*8 + ri] = z;
    ws_fr[(size_t)m*8 + ri] = fr;
    ws_st[(size_t)m*8 + ri] = st;
    double b = cl[deg];
    double nc[8];
#pragma unroll
    for (int j=deg-1;j>=1;j--){
      double bn = cl[j] + z*b;
      nc[j] = b;
      b = bn;
    }
    nc[0] = b;
#pragma unroll
    for (int j=0;j<deg;j++) cl[j] = nc[j];
  }
}

// ---------------------------------------------------------------------------
// k3: polish (f64, lane r = root r) + f32 resolvent with M2..M8 in LDS slots
// (no M[7][8] reg array) + NS + outputs. Structure == R4's kB (correctness
// proven by the R4 pass); block=128 (16 matrices, 28.9 KB LDS -> 5 blocks/CU)
// and a[] reloaded late. No phase exceeds ~60 live VGPRs.
// ---------------------------------------------------------------------------
__global__ __launch_bounds__(128)
void k3_eig(const float* __restrict__ A, const double* __restrict__ ws_c,
            const double* __restrict__ ws_lam, const double* __restrict__ ws_scale,
            const float* __restrict__ ws_fr, const float* __restrict__ ws_st,
            float* __restrict__ out, int B)
{
#pragma clang fp contract(off)
  __shared__ float SB[16*452];   // 28928 B: 7 M-slots x 64 + 4 pad per matrix
  int t = blockIdx.x*128 + threadIdx.x;
  int m = t >> 3, r = t & 7;
  bool act = (m < B);
  if (!act) m = 0;
  int ml = threadIdx.x >> 3;     // 0..15
  float* Sm = SB + ml*452;

  // ---- Newton polish: lane r polishes root r (bitwise op order) ----
  const double* cp = ws_c + (size_t)m*9;
  double cd[8];
#pragma unroll
  for (int j=0;j<8;j++) cd[j] = cp[j];
  double z = ws_lam[(size_t)m*8 + r];
#pragma unroll
  for (int it=0; it<3; it++){
    double pv = 1.0, dp = 0.0;
#pragma unroll
    for (int j=7;j>=0;j--){
      dp = dp*z + pv;
      pv = pv*z + cd[j];
    }
    bool ok = fabs(dp) > 1e-30;
    double dps = ok ? dp : 1.0;
    z = z - (ok ? pv/dps : 0.0);
  }
  float lamf[8];
#pragma unroll
  for (int j=0;j<8;j++) lamf[j] = (float)shfl8d(z, j);
  float cc[8];
#pragma unroll
  for (int j=1;j<8;j++) cc[j] = (float)cd[j];

  float sc = (float)ws_scale[m];
  float Af[8];
  {
    const float* Am = A + (size_t)m*64 + (size_t)r*8;
#pragma unroll
    for (int j=0;j<8;j++) Af[j] = Am[j] / sc;
  }

  // ---- M2..M8 chain, each M_k parked in LDS slot k-2 ----
  float Mc[8];
#pragma unroll
  for (int j=0;j<8;j++) Mc[j] = Af[j] + ((j==r) ? cc[7] : 0.0f);
  {
    float4* w = (float4*)(Sm + 0*64 + r*8);
    w[0] = make_float4(Mc[0],Mc[1],Mc[2],Mc[3]);
    w[1] = make_float4(Mc[4],Mc[5],Mc[6],Mc[7]);
  }
  __syncthreads();
#pragma unroll
  for (int k=3;k<=8;k++){
    float ckf = cc[9-k];
    float Mn[8];
#pragma unroll
    for (int kk=0;kk<8;kk++){
      const float4* rp = (const float4*)(Sm + (k-3)*64 + kk*8);
      float4 lo = rp[0], hi = rp[1];
      if (kk == 0){
        Mn[0]=Af[0]*lo.x; Mn[1]=Af[0]*lo.y; Mn[2]=Af[0]*lo.z; Mn[3]=Af[0]*lo.w;
        Mn[4]=Af[0]*hi.x; Mn[5]=Af[0]*hi.y; Mn[6]=Af[0]*hi.z; Mn[7]=Af[0]*hi.w;
      } else {
        Mn[0]=fmaf(Af[kk],lo.x,Mn[0]); Mn[1]=fmaf(Af[kk],lo.y,Mn[1]);
        Mn[2]=fmaf(Af[kk],lo.z,Mn[2]); Mn[3]=fmaf(Af[kk],lo.w,Mn[3]);
        Mn[4]=fmaf(Af[kk],hi.x,Mn[4]); Mn[5]=fmaf(Af[kk],hi.y,Mn[5]);
        Mn[6]=fmaf(Af[kk],hi.z,Mn[6]); Mn[7]=fmaf(Af[kk],hi.w,Mn[7]);
      }
    }
#pragma unroll
    for (int j=0;j<8;j++) Mc[j] = Mn[j] + ((j==r) ? ckf : 0.0f);
    {
      float4* w = (float4*)(Sm + (k-2)*64 + r*8);
      w[0] = make_float4(Mc[0],Mc[1],Mc[2],Mc[3]);
      w[1] = make_float4(Mc[4],Mc[5],Mc[6],Mc[7]);
    }
    __syncthreads();
  }

  // ---- resolvent: 4 passes x 2 eigenvalues, M rows streamed from LDS ----
  float Vrow[8];
#pragma unroll
  for (int p=0;p<4;p++){
    float l0 = lamf[2*p], l1 = lamf[2*p+1];
    float R0[8], R1[8];
#pragma unroll
    for (int j=0;j<8;j++){ R0[j] = (j==r) ? 1.0f : 0.0f; R1[j] = R0[j]; }
#pragma unroll
    for (int k=0;k<7;k++){
      const float4* rp = (const float4*)(Sm + k*64 + r*8);
      float4 lo = rp[0], hi = rp[1];
      float row[8] = {lo.x,lo.y,lo.z,lo.w,hi.x,hi.y,hi.z,hi.w};
#pragma unroll
      for (int j=0;j<8;j++){
        R0[j] = fmaf(R0[j], l0, row[j]);
        R1[j] = fmaf(R1[j], l1, row[j]);
      }
    }
#pragma unroll
    for (int e=0;e<2;e++){
      float* R = (e==0) ? R0 : R1;
      float nsq = R[0]*R[0];
#pragma unroll
      for (int j=1;j<8;j++) nsq = fmaf(R[j], R[j], nsq);
      int bi = r; float bv = nsq;
#pragma unroll
      for (int lvl=1; lvl<8; lvl<<=1){
        float ov = xor8f(bv, lvl);
        int   oi = xor8i(bi, lvl);
        bool take = (ov > bv) || ((ov == bv) && (oi < bi));
        bv = take ? ov : bv;
        bi = take ? oi : bi;
      }
      float vr = sel8f(R, bi);
      float nn = sqrtf(bv);
      Vrow[2*p+e] = vr / (nn + 1e-30f);
    }
  }

  // ---- NS phase: alias the (now dead) M region ----
  __syncthreads();
  float* mV = SB + 0*1152 + ml*72;
  float* mY = SB + 1*1152 + ml*72;
  float* mT = SB + 2*1152 + ml*72;
  float* mX = SB + 3*1152 + ml*72;
#pragma unroll
  for (int j=0;j<8;j++) mV[r*9+j] = Vrow[j];
  __syncthreads();
  float Yrow[8];
#pragma unroll
  for (int j=0;j<8;j++){
    float s = 0.0f;
#pragma unroll
    for (int k=0;k<8;k++) s = fmaf(mV[k*9+r], mV[k*9+j], s);
    Yrow[j] = s;
  }
  float Xrow[8];
#pragma unroll
  for (int j=0;j<8;j++) Xrow[j] = (j==r) ? 1.0f : 0.0f;
#pragma unroll
  for (int j=0;j<8;j++) mY[r*9+j] = Yrow[j];
  __syncthreads();
#pragma unroll
  for (int it=0; it<2; it++){
    float Trow[8];
#pragma unroll
    for (int j=0;j<8;j++) Trow[j] = ((j==r) ? 3.0f : 0.0f) - Yrow[j];
#pragma unroll
    for (int j=0;j<8;j++) mT[r*9+j] = Trow[j];
    __syncthreads();
    float Xn[8], Yn[8];
#pragma unroll
    for (int j=0;j<8;j++){
      float s = 0.0f;
#pragma unroll
      for (int k=0;k<8;k++) s = fmaf(Xrow[k], mT[k*9+j], s);
      Xn[j] = 0.5f*s;
    }
#pragma unroll
    for (int j=0;j<8;j++){
      float s = 0.0f;
#pragma unroll
      for (int k=0;k<8;k++) s = fmaf(Trow[k], mY[k*9+j], s);
      Yn[j] = 0.5f*s;
    }
    __syncthreads();
#pragma unroll
    for (int j=0;j<8;j++){ mY[r*9+j] = Yn[j]; Yrow[j] = Yn[j]; Xrow[j] = Xn[j]; }
    __syncthreads();
  }
#pragma unroll
  for (int j=0;j<8;j++) mX[r*9+j] = Xrow[j];
  __syncthreads();
  float Vn[8];
#pragma unroll
  for (int j=0;j<8;j++){
    float s = 0.0f;
#pragma unroll
    for (int k=0;k<8;k++) s = fmaf(Vrow[k], mX[k*9+j], s);
    Vn[j] = s;
  }
  __syncthreads();
#pragma unroll
  for (int j=0;j<8;j++) mV[r*9+j] = Vn[j];
  __syncthreads();
  float Erow[8];
#pragma unroll
  for (int j=0;j<8;j++){
    float s = 0.0f;
#pragma unroll
    for (int k=0;k<8;k++) s = fmaf(mV[k*9+r], mV[k*9+j], s);
    Erow[j] = s - ((j==r) ? 1.0f : 0.0f);
  }
  float rs = Erow[0]*Erow[0];
#pragma unroll
  for (int j=1;j<8;j++) rs = rs + Erow[j]*Erow[j];
  rs = rs + xor8f(rs,1);
  rs = rs + xor8f(rs,2);
  rs = rs + xor8f(rs,4);
  float resid = sqrtf(rs);
  // reload a late (L2-hot) for AV
  float a[8];
  {
    const float* Am = A + (size_t)m*64 + (size_t)r*8;
#pragma unroll
    for (int j=0;j<8;j++) a[j] = Am[j];
  }
  float AVrow[8];
#pragma unroll
  for (int j=0;j<8;j++){
    float s = 0.0f;
#pragma unroll
    for (int k=0;k<8;k++) s = fmaf(a[k], mV[k*9+j], s);
    AVrow[j] = s;
  }
  float q[8];
#pragma unroll
  for (int i=0;i<8;i++) q[i] = Vn[i]*AVrow[i];
  float ev[8];
#pragma unroll
  for (int i=0;i<8;i++){
    float s = shfl8f(q[i], 0);
#pragma unroll
    for (int k=1;k<8;k++) s = s + shfl8f(q[i], k);
    ev[i] = s;
  }
  int perm[8];
  unsigned used = 0;
#pragma unroll
  for (int p=0;p<8;p++){
    int bi2 = -1; float bvv = 0.0f;
#pragma unroll
    for (int i2=0;i2<8;i2++){
      bool u = (used >> i2) & 1u;
      bool take = !u && (bi2 < 0 || ev[i2] < bvv);
      bi2 = take ? i2 : bi2;
      bvv = take ? ev[i2] : bvv;
    }
    perm[p] = bi2;
    used |= (1u << bi2);
  }
  int oi = sel8i(perm, r);
  float col[8];
#pragma unroll
  for (int j=0;j<8;j++) col[j] = mV[j*9 + oi];
  int mi = 0; float mv = fabsf(col[0]);
#pragma unroll
  for (int j=1;j<8;j++){
    float aj = fabsf(col[j]);
    if (aj > mv){ mv = aj; mi = j; }
  }
  float v0 = sel8f(col, mi);
  float sgn = (v0 > 0.0f) ? 1.0f : ((v0 < 0.0f) ? -1.0f : v0);
  if (act){
    out[(size_t)m*8 + r] = sel8f(ev, oi);                          // se
    float* svp = out + (size_t)B*8 + (size_t)m*64;                 // sv
#pragma unroll
    for (int j=0;j<8;j++) svp[(size_t)j*8 + r] = col[j]*sgn;
    out[(size_t)B*80 + (size_t)m*8 + r] = ws_fr[(size_t)m*8 + oi]; // friction_s
    out[(size_t)B*88 + (size_t)m*8 + r] = ws_st[(size_t)m*8 + oi]; // settle_s
    out[(size_t)B*96 + (size_t)m*8 + r] = (float)r;                // extraction_order
    if (r == 0) out[(size_t)B*104 + m] = resid;                    // residual
  }
}

extern "C" void kernel_launch(void* const* d_in, const int* in_sizes, int n_in,
                              void* d_out, int out_size, void* d_ws, size_t ws_size,
                              hipStream_t stream) {
  const float* A = (const float*)d_in[0];
  int B = in_sizes[0] / 64;
  float* out = (float*)d_out;

  double* ws_c     = (double*)d_ws;                 // B*9 f64
  double* ws_zi    = ws_c   + (size_t)B*9;          // B*8 f64
  double* ws_lam   = ws_zi  + (size_t)B*8;          // B*8 f64 (unpolished)
  double* ws_scale = ws_lam + (size_t)B*8;          // B   f64
  float*  ws_fr    = (float*)(ws_scale + B);        // B*8 f32
  float*  ws_st    = ws_fr  + (size_t)B*8;          // B*8 f32

  int nt = B*8;
  hipLaunchKernelGGL(k1_chain, dim3((nt+255)/256), dim3(256), 0, stream,
                     A, ws_c, ws_zi, ws_scale, out + (size_t)B*72, B);
  hipLaunchKernelGGL(k2_rings, dim3((B+255)/256), dim3(256), 0, stream,
                     ws_c, ws_zi, ws_lam, ws_fr, ws_st, B);
  hipLaunchKernelGGL(k3_eig, dim3((nt+127)/128), dim3(128), 0, stream,
                     A, ws_c, ws_lam, ws_scale, ws_fr, ws_st, out, B);
}